// Round 1
// baseline (758.141 us; speedup 1.0000x reference)
//
#include <hip/hip_runtime.h>
#include <hip/hip_bf16.h>
#include <stdint.h>

// Problem dims (ConvDecoderLayer): B=8, T=S=2048, D=512, K=3
// out = (LN2(h + (attn@v)@Wo^T + bo), attn), h = LN1(GLU(causal_conv(x)) + x)
// Workspace use ~197 MB.

typedef unsigned short ushortT;
typedef __bf16 bf16x8 __attribute__((ext_vector_type(8)));
typedef float floatx4 __attribute__((ext_vector_type(4)));
typedef float floatx8 __attribute__((ext_vector_type(8)));
typedef unsigned short ushort8 __attribute__((ext_vector_type(8)));

__device__ __forceinline__ ushortT f2bf(float f) {
  unsigned u = __builtin_bit_cast(unsigned, f);
  u += 0x7FFFu + ((u >> 16) & 1u);   // round-to-nearest-even
  return (ushortT)(u >> 16);
}

// ---------------- conversion kernels ----------------
__global__ __launch_bounds__(256) void k_f32_to_bf16(const float* __restrict__ src,
                                                     ushortT* __restrict__ dst, long n) {
  long i = (long)blockIdx.x * 256 + threadIdx.x;
  if (i < n) dst[i] = f2bf(src[i]);
}

// conv_w [1024][512][3] -> Wc [1024][1536], c = tap*512 + i
__global__ __launch_bounds__(256) void k_convw(const float* __restrict__ w,
                                               ushortT* __restrict__ dst) {
  long idx = (long)blockIdx.x * 256 + threadIdx.x;
  if (idx >= 1024L * 1536) return;
  int o = (int)(idx / 1536), c = (int)(idx % 1536);
  int tap = c >> 9, i = c & 511;
  dst[idx] = f2bf(w[(o * 512 + i) * 3 + tap]);
}

// ---------------- GEMM ----------------
// C[M,N] = scale * A[M,K] @ B_op + bias
// A_F32: A is float (converted to bf16 during staging); else A is bf16 (ushort).
// CONV_A: A is the virtual causal-conv matrix built from fp32 x [8,2048,512]:
//         A[r][c] = x[b=r>>11, t=(r&2047)+ (c>>9) - 2, i=c&511] (0 if t'<0)
// NN_B=0: B stored [N,K] row-major (B^T form). NN_B=1: B stored [K,N].
// WRITE_BF16: write bf16 to Cb, else fp32 to Cf.
template<int A_F32, int CONV_A, int NN_B, int HAS_BIAS, int WRITE_BF16>
__global__ __launch_bounds__(256)
void k_gemm(const void* __restrict__ A, long aBatch, int lda,
            const ushortT* __restrict__ Bm, long bBatch, int ldb,
            const float* __restrict__ bias,
            float* __restrict__ Cf, ushortT* __restrict__ Cb, long cBatch, int ldc,
            int Kdim, float scale)
{
  __shared__ ushortT As[128 * 32];
  __shared__ ushortT Bs[128 * 32];
  const int tid  = threadIdx.x;
  const int lane = tid & 63;
  const int wave = tid >> 6;
  const int wrow = (wave >> 1) * 64;
  const int wcol = (wave & 1) * 64;
  const int l15  = lane & 15;
  const int quad = lane >> 4;
  const long zA = (long)blockIdx.z * aBatch;
  const long zB = (long)blockIdx.z * bBatch;
  const long zC = (long)blockIdx.z * cBatch;
  const int rowBase = blockIdx.x * 128;
  const int colBase = blockIdx.y * 128;

  const ushortT* Au = (const ushortT*)A;
  const float*   Af = (const float*)A;

  floatx4 zero = {0.f, 0.f, 0.f, 0.f};
  floatx4 acc[4][4];
#pragma unroll
  for (int mi = 0; mi < 4; mi++)
#pragma unroll
    for (int ni = 0; ni < 4; ni++) acc[mi][ni] = zero;

  for (int k0 = 0; k0 < Kdim; k0 += 32) {
    __syncthreads();
    // ---- stage A tile [128 rows][32 k] ----
    {
      int ch = tid;
#pragma unroll
      for (int it = 0; it < 2; it++, ch += 256) {
        int row = ch >> 2, c8 = (ch & 3) << 3;
        int gr = rowBase + row;
        int gc = k0 + c8;
        ushort8 v = {0, 0, 0, 0, 0, 0, 0, 0};
        if (CONV_A) {
          int tap = gc >> 9, ii = gc & 511;
          int b = gr >> 11, t = gr & 2047;
          int st = t + tap - 2;
          if (st >= 0) {
            floatx8 fv = *(const floatx8*)&Af[((long)(b << 11) + st) * 512 + ii];
#pragma unroll
            for (int j = 0; j < 8; j++) v[j] = f2bf(fv[j]);
          }
        } else if (A_F32) {
          floatx8 fv = *(const floatx8*)&Af[zA + (long)gr * lda + gc];
#pragma unroll
          for (int j = 0; j < 8; j++) v[j] = f2bf(fv[j]);
        } else {
          v = *(const ushort8*)&Au[zA + (long)gr * lda + gc];
        }
        *(ushort8*)&As[row * 32 + c8] = v;
      }
    }
    // ---- stage B tile into Bs[n][k] ----
    if (!NN_B) {
      int ch = tid;
#pragma unroll
      for (int it = 0; it < 2; it++, ch += 256) {
        int row = ch >> 2, c8 = (ch & 3) << 3;   // row = n
        ushort8 v = *(const ushort8*)&Bm[zB + (long)(colBase + row) * ldb + k0 + c8];
        *(ushort8*)&Bs[row * 32 + c8] = v;
      }
    } else {
      int ch = tid;
#pragma unroll
      for (int it = 0; it < 2; it++, ch += 256) {
        int kk = ch >> 4, c8n = (ch & 15) << 3;
        ushort8 v = *(const ushort8*)&Bm[zB + (long)(k0 + kk) * ldb + colBase + c8n];
#pragma unroll
        for (int j = 0; j < 8; j++) Bs[(c8n + j) * 32 + kk] = v[j];
      }
    }
    __syncthreads();
    // ---- MFMA ----
    bf16x8 av[4], bv[4];
#pragma unroll
    for (int mi = 0; mi < 4; mi++)
      av[mi] = *(const bf16x8*)&As[(wrow + mi * 16 + l15) * 32 + quad * 8];
#pragma unroll
    for (int ni = 0; ni < 4; ni++)
      bv[ni] = *(const bf16x8*)&Bs[(wcol + ni * 16 + l15) * 32 + quad * 8];
#pragma unroll
    for (int mi = 0; mi < 4; mi++)
#pragma unroll
      for (int ni = 0; ni < 4; ni++)
        acc[mi][ni] = __builtin_amdgcn_mfma_f32_16x16x32_bf16(av[mi], bv[ni], acc[mi][ni], 0, 0, 0);
  }

  // ---- epilogue ----
#pragma unroll
  for (int mi = 0; mi < 4; mi++) {
#pragma unroll
    for (int ni = 0; ni < 4; ni++) {
      int gcol = colBase + wcol + ni * 16 + l15;
      float bsv = HAS_BIAS ? bias[gcol] : 0.0f;
#pragma unroll
      for (int r = 0; r < 4; r++) {
        int grow = rowBase + wrow + mi * 16 + quad * 4 + r;
        float val = acc[mi][ni][r] * scale + bsv;
        long off = zC + (long)grow * ldc + gcol;
        if (WRITE_BF16) Cb[off] = f2bf(val);
        else            Cf[off] = val;
      }
    }
  }
}

// ---------------- GLU + residual + LN1 ----------------
__global__ __launch_bounds__(256)
void k_glu_ln(const float* __restrict__ conv, const float* __restrict__ x,
              const float* __restrict__ w, const float* __restrict__ b,
              float* __restrict__ h, ushortT* __restrict__ hbf)
{
  __shared__ float s1[4], s2[4];
  long r = blockIdx.x;
  const float* crow = conv + r * 1024;
  const float* xrow = x + r * 512;
  int tid = threadIdx.x;
  float y[2];
  float sum = 0.f, ssq = 0.f;
#pragma unroll
  for (int j = 0; j < 2; j++) {
    int d = tid + j * 256;
    float a = crow[d], g = crow[d + 512];
    float v = a / (1.0f + __expf(-g)) + xrow[d];
    y[j] = v; sum += v; ssq += v * v;
  }
#pragma unroll
  for (int off = 32; off; off >>= 1) { sum += __shfl_xor(sum, off); ssq += __shfl_xor(ssq, off); }
  if ((tid & 63) == 0) { s1[tid >> 6] = sum; s2[tid >> 6] = ssq; }
  __syncthreads();
  sum = s1[0] + s1[1] + s1[2] + s1[3];
  ssq = s2[0] + s2[1] + s2[2] + s2[3];
  float mu = sum * (1.0f / 512.0f);
  float var = ssq * (1.0f / 512.0f) - mu * mu;
  float rstd = rsqrtf(var + 1e-5f);
#pragma unroll
  for (int j = 0; j < 2; j++) {
    int d = tid + j * 256;
    float val = (y[j] - mu) * rstd * w[d] + b[d];
    h[r * 512 + d] = val;
    hbf[r * 512 + d] = f2bf(val);
  }
}

// ---------------- residual + LN2 ----------------
__global__ __launch_bounds__(256)
void k_add_ln(const float* __restrict__ h, const float* __restrict__ c,
              const float* __restrict__ w, const float* __restrict__ b,
              float* __restrict__ out)
{
  __shared__ float s1[4], s2[4];
  long r = blockIdx.x;
  int tid = threadIdx.x;
  float y[2];
  float sum = 0.f, ssq = 0.f;
#pragma unroll
  for (int j = 0; j < 2; j++) {
    int d = tid + j * 256;
    float v = h[r * 512 + d] + c[r * 512 + d];
    y[j] = v; sum += v; ssq += v * v;
  }
#pragma unroll
  for (int off = 32; off; off >>= 1) { sum += __shfl_xor(sum, off); ssq += __shfl_xor(ssq, off); }
  if ((tid & 63) == 0) { s1[tid >> 6] = sum; s2[tid >> 6] = ssq; }
  __syncthreads();
  sum = s1[0] + s1[1] + s1[2] + s1[3];
  ssq = s2[0] + s2[1] + s2[2] + s2[3];
  float mu = sum * (1.0f / 512.0f);
  float var = ssq * (1.0f / 512.0f) - mu * mu;
  float rstd = rsqrtf(var + 1e-5f);
#pragma unroll
  for (int j = 0; j < 2; j++) {
    int d = tid + j * 256;
    out[r * 512 + d] = (y[j] - mu) * rstd * w[d] + b[d];
  }
}

// ---------------- softmax over S=2048, in place ----------------
__global__ __launch_bounds__(256)
void k_softmax(float* __restrict__ attn)
{
  __shared__ float sred[4];
  long r = blockIdx.x;
  float* row = attn + r * 2048;
  int tid = threadIdx.x;
  float v[8];
  float mx = -1e30f;
#pragma unroll
  for (int j = 0; j < 8; j++) { v[j] = row[tid + j * 256]; mx = fmaxf(mx, v[j]); }
#pragma unroll
  for (int off = 32; off; off >>= 1) mx = fmaxf(mx, __shfl_xor(mx, off));
  if ((tid & 63) == 0) sred[tid >> 6] = mx;
  __syncthreads();
  mx = fmaxf(fmaxf(sred[0], sred[1]), fmaxf(sred[2], sred[3]));
  __syncthreads();
  float sum = 0.f;
#pragma unroll
  for (int j = 0; j < 8; j++) { v[j] = __expf(v[j] - mx); sum += v[j]; }
#pragma unroll
  for (int off = 32; off; off >>= 1) sum += __shfl_xor(sum, off);
  if ((tid & 63) == 0) sred[tid >> 6] = sum;
  __syncthreads();
  sum = sred[0] + sred[1] + sred[2] + sred[3];
  float inv = 1.0f / sum;
#pragma unroll
  for (int j = 0; j < 8; j++) row[tid + j * 256] = v[j] * inv;
}

extern "C" void kernel_launch(void* const* d_in, const int* in_sizes, int n_in,
                              void* d_out, int out_size, void* d_ws, size_t ws_size,
                              hipStream_t stream)
{
  const float* x      = (const float*)d_in[0];
  const float* enc    = (const float*)d_in[1];
  const float* conv_w = (const float*)d_in[2];
  const float* conv_b = (const float*)d_in[3];
  const float* ln1_w  = (const float*)d_in[4];
  const float* ln1_b  = (const float*)d_in[5];
  const float* Wq     = (const float*)d_in[6];
  const float* bq     = (const float*)d_in[7];
  const float* Wk     = (const float*)d_in[8];
  const float* bk     = (const float*)d_in[9];
  const float* Wv     = (const float*)d_in[10];
  const float* bv     = (const float*)d_in[11];
  const float* Wo     = (const float*)d_in[12];
  const float* bo     = (const float*)d_in[13];
  const float* ln2_w  = (const float*)d_in[14];
  const float* ln2_b  = (const float*)d_in[15];

  const long BT = 16384, Dd = 512, S = 2048, TT = 2048;
  float* out  = (float*)d_out;
  float* attn = out + BT * Dd;     // second output region [B,T,S]

  char* p = (char*)d_ws;
  auto alloc = [&](size_t bytes) { char* r = p; p += (bytes + 255) & ~255UL; return r; };
  float*  h_f   = (float*)alloc(BT * Dd * 4);
  float*  convb = (float*)alloc(BT * 1024 * 4);   // conv pre-GLU; later reused as ctxo
  ushortT* encbf = (ushortT*)alloc(BT * Dd * 2);
  ushortT* hbf   = (ushortT*)alloc(BT * Dd * 2);
  ushortT* qbf   = (ushortT*)alloc(BT * Dd * 2);
  ushortT* kbf   = (ushortT*)alloc(BT * Dd * 2);
  ushortT* vbf   = (ushortT*)alloc(BT * Dd * 2);
  ushortT* ctxbf = (ushortT*)alloc(BT * Dd * 2);
  ushortT* Wcbf  = (ushortT*)alloc(1024L * 1536 * 2);
  ushortT* Wqbf  = (ushortT*)alloc(Dd * Dd * 2);
  ushortT* Wkbf  = (ushortT*)alloc(Dd * Dd * 2);
  ushortT* Wvbf  = (ushortT*)alloc(Dd * Dd * 2);
  ushortT* Wobf  = (ushortT*)alloc(Dd * Dd * 2);

  // conversions
  long nx = BT * Dd;
  k_f32_to_bf16<<<(nx + 255) / 256, 256, 0, stream>>>(enc, encbf, nx);
  k_convw<<<(1024 * 1536 + 255) / 256, 256, 0, stream>>>(conv_w, Wcbf);
  k_f32_to_bf16<<<(Dd * Dd + 255) / 256, 256, 0, stream>>>(Wq, Wqbf, Dd * Dd);
  k_f32_to_bf16<<<(Dd * Dd + 255) / 256, 256, 0, stream>>>(Wk, Wkbf, Dd * Dd);
  k_f32_to_bf16<<<(Dd * Dd + 255) / 256, 256, 0, stream>>>(Wv, Wvbf, Dd * Dd);
  k_f32_to_bf16<<<(Dd * Dd + 255) / 256, 256, 0, stream>>>(Wo, Wobf, Dd * Dd);

  // conv GEMM: [16384,1536] x Wc^T[1536,1024] -> convb fp32
  {
    dim3 g(128, 8, 1);
    k_gemm<1, 1, 0, 1, 0><<<g, 256, 0, stream>>>(x, 0, 0, Wcbf, 0, 1536, conv_b,
                                                 convb, nullptr, 0, 1024, 1536, 1.0f);
  }
  // GLU + residual + LN1 -> h (fp32) + hbf
  k_glu_ln<<<16384, 256, 0, stream>>>(convb, x, ln1_w, ln1_b, h_f, hbf);

  // q/k/v projections (B^T form, bias, bf16 out)
  {
    dim3 g(128, 4, 1);
    k_gemm<0, 0, 0, 1, 1><<<g, 256, 0, stream>>>(hbf, 0, 512, Wqbf, 0, 512, bq,
                                                 nullptr, qbf, 0, 512, 512, 1.0f);
    k_gemm<0, 0, 0, 1, 1><<<g, 256, 0, stream>>>(encbf, 0, 512, Wkbf, 0, 512, bk,
                                                 nullptr, kbf, 0, 512, 512, 1.0f);
    k_gemm<0, 0, 0, 1, 1><<<g, 256, 0, stream>>>(encbf, 0, 512, Wvbf, 0, 512, bv,
                                                 nullptr, vbf, 0, 512, 512, 1.0f);
  }
  // scores = q @ k^T / sqrt(512) -> attn region (fp32), batched over 8
  {
    dim3 g(16, 16, 8);
    k_gemm<0, 0, 0, 0, 0><<<g, 256, 0, stream>>>(qbf, TT * Dd, 512, kbf, S * Dd, 512, nullptr,
                                                 attn, nullptr, TT * S, 2048, 512,
                                                 0.04419417382415922f);
  }
  // softmax rows (in place on d_out attn region)
  k_softmax<<<16384, 256, 0, stream>>>(attn);

  // ctx = attn @ v  (A fp32 from d_out, B in [K,N] form) -> ctxbf
  {
    dim3 g(16, 4, 8);
    k_gemm<1, 0, 1, 0, 1><<<g, 256, 0, stream>>>(attn, TT * S, 2048, vbf, S * Dd, 512, nullptr,
                                                 nullptr, ctxbf, TT * Dd, 512, 2048, 1.0f);
  }
  // out-proj: ctx @ Wo^T + bo -> ctxo (reuse convb)
  float* ctxo = convb;
  {
    dim3 g(128, 4, 1);
    k_gemm<0, 0, 0, 1, 0><<<g, 256, 0, stream>>>(ctxbf, 0, 512, Wobf, 0, 512, bo,
                                                 ctxo, nullptr, 0, 512, 512, 1.0f);
  }
  // LN2 -> out
  k_add_ln<<<16384, 256, 0, stream>>>(h_f, ctxo, ln2_w, ln2_b, out);
}

// Round 2
// 609.253 us; speedup vs baseline: 1.2444x; 1.2444x over previous
//
#include <hip/hip_runtime.h>
#include <hip/hip_bf16.h>
#include <stdint.h>

// ConvDecoderLayer: B=8, T=S=2048, D=512, K=3
// out = (LN2(h + (attn@v)@Wo^T + bo), attn), h = LN1(GLU(causal_conv(x)) + x)

typedef unsigned short ushortT;
typedef __bf16 bf16x8 __attribute__((ext_vector_type(8)));
typedef float floatx4 __attribute__((ext_vector_type(4)));
typedef unsigned short ushort4v __attribute__((ext_vector_type(4)));
typedef unsigned short ushort8 __attribute__((ext_vector_type(8)));

__device__ __forceinline__ ushortT f2bf(float f) {
  unsigned u = __builtin_bit_cast(unsigned, f);
  u += 0x7FFFu + ((u >> 16) & 1u);   // RNE
  return (ushortT)(u >> 16);
}

__device__ __forceinline__ void gload_lds16(const void* g, void* l) {
  __builtin_amdgcn_global_load_lds(
      (const __attribute__((address_space(1))) void*)g,
      (__attribute__((address_space(3))) void*)l, 16, 0, 0);
}

// ---------------- conversion kernels ----------------
__global__ __launch_bounds__(256)
void k_f32_to_bf16v(const float* __restrict__ src, ushortT* __restrict__ dst, long n4) {
  long i = (long)blockIdx.x * 256 + threadIdx.x;
  if (i >= n4) return;
  floatx4 v = *(const floatx4*)&src[i * 4];
  ushort4v o;
#pragma unroll
  for (int j = 0; j < 4; j++) o[j] = f2bf(v[j]);
  *(ushort4v*)&dst[i * 4] = o;
}

// x [8,2048,512] f32 -> xpad [8,2050,512] bf16 with 2 leading zero rows per batch
__global__ __launch_bounds__(128)
void k_xpad(const float* __restrict__ x, ushortT* __restrict__ xp) {
  int row = blockIdx.x;                 // 8*2050
  int b = row / 2050, tp = row % 2050;
  int c = threadIdx.x * 4;
  ushort4v o = {0, 0, 0, 0};
  if (tp >= 2) {
    floatx4 v = *(const floatx4*)&x[((long)(b * 2048 + tp - 2)) * 512 + c];
#pragma unroll
    for (int j = 0; j < 4; j++) o[j] = f2bf(v[j]);
  }
  *(ushort4v*)&xp[(long)row * 512 + c] = o;
}

// conv_w [1024][512][3] -> interleaved B^T form Wc'[n][kk], kk = tap*512+i
// column n: p=n>>5, which=(n>>4)&1, idx=n&15 -> orig o = which*512 + p*16 + idx
__global__ __launch_bounds__(256)
void k_convw(const float* __restrict__ w, ushortT* __restrict__ dst) {
  long idx = (long)blockIdx.x * 256 + threadIdx.x;
  if (idx >= 1024L * 1536) return;
  int n = (int)(idx / 1536), kk = (int)(idx % 1536);
  int tap = kk >> 9, i = kk & 511;
  int o = ((n >> 4) & 1) * 512 + (n >> 5) * 16 + (n & 15);
  dst[idx] = f2bf(w[(o * 512 + i) * 3 + tap]);
}

// ---------------- GEMM ----------------
// C[M,N] = scale * A[M,K] @ B^T + bias ; A,B bf16, staged via global_load_lds(16B)
// CONV_A: A built from xpad (causal conv virtual matrix), A ptr = xpad
// BIAS: 0 none, 1 per-col, 2 per-row
// GLU: epilogue computes a*sigmoid(g)+xres with interleaved columns, writes fp32 [.,512]
// WBF16: write bf16 else fp32
template<int CONV_A, int BIAS, int GLU, int WBF16>
__global__ __launch_bounds__(256)
void k_gemm(const ushortT* __restrict__ A, long aBatch, int lda,
            const ushortT* __restrict__ Bm, long bBatch, int ldb,
            const float* __restrict__ bias, const float* __restrict__ xres,
            float* __restrict__ Cf, ushortT* __restrict__ Cb, long cBatch, int ldc,
            int Kdim, float scale)
{
  __shared__ ushortT As[128 * 32];
  __shared__ ushortT Bs[128 * 32];
  const int tid  = threadIdx.x;
  const int lane = tid & 63;
  const int wave = tid >> 6;
  const int wrow = (wave >> 1) * 64;
  const int wcol = (wave & 1) * 64;
  const int l15  = lane & 15;
  const int quad = lane >> 4;
  const long zA = (long)blockIdx.z * aBatch;
  const long zB = (long)blockIdx.z * bBatch;
  const long zC = (long)blockIdx.z * cBatch;
  const int rowBase = blockIdx.x * 128;
  const int colBase = blockIdx.y * 128;

  floatx4 zero = {0.f, 0.f, 0.f, 0.f};
  floatx4 acc[4][4];
#pragma unroll
  for (int mi = 0; mi < 4; mi++)
#pragma unroll
    for (int ni = 0; ni < 4; ni++) acc[mi][ni] = zero;

  for (int k0 = 0; k0 < Kdim; k0 += 32) {
    __syncthreads();
    {
      int ch = tid;
#pragma unroll
      for (int it = 0; it < 2; it++, ch += 256) {
        int row = ch >> 2, c8 = (ch & 3) << 3;
        if (CONV_A) {
          int gr = rowBase + row, gc = k0 + c8;
          int tap = gc >> 9, ii = gc & 511;
          int b = gr >> 11, t = gr & 2047;
          long gofs = ((long)(b * 2050 + t + tap) << 9) + ii;
          gload_lds16(A + gofs, &As[ch * 8]);
        } else {
          long gofs = zA + (long)(rowBase + row) * lda + (k0 + c8);
          gload_lds16(A + gofs, &As[ch * 8]);
        }
      }
      ch = tid;
#pragma unroll
      for (int it = 0; it < 2; it++, ch += 256) {
        int row = ch >> 2, c8 = (ch & 3) << 3;
        long gofs = zB + (long)(colBase + row) * ldb + (k0 + c8);
        gload_lds16(Bm + gofs, &Bs[ch * 8]);
      }
    }
    __syncthreads();
    bf16x8 av[4], bv[4];
#pragma unroll
    for (int mi = 0; mi < 4; mi++)
      av[mi] = *(const bf16x8*)&As[(wrow + mi * 16 + l15) * 32 + quad * 8];
#pragma unroll
    for (int ni = 0; ni < 4; ni++)
      bv[ni] = *(const bf16x8*)&Bs[(wcol + ni * 16 + l15) * 32 + quad * 8];
#pragma unroll
    for (int mi = 0; mi < 4; mi++)
#pragma unroll
      for (int ni = 0; ni < 4; ni++)
        acc[mi][ni] = __builtin_amdgcn_mfma_f32_16x16x32_bf16(av[mi], bv[ni], acc[mi][ni], 0, 0, 0);
  }

  if (GLU) {
    // interleaved: ni even holds a-block, ni odd holds g-block of pair group p
#pragma unroll
    for (int mi = 0; mi < 4; mi++) {
#pragma unroll
      for (int ni = 0; ni < 4; ni += 2) {
        int colA = colBase + wcol + ni * 16;
        int d = (colA >> 5) * 16 + l15;
        float ba = bias[d], bg = bias[512 + d];
#pragma unroll
        for (int r = 0; r < 4; r++) {
          int grow = rowBase + wrow + mi * 16 + quad * 4 + r;
          float a = acc[mi][ni][r] + ba;
          float g = acc[mi][ni + 1][r] + bg;
          float val = a / (1.0f + __expf(-g)) + xres[(long)grow * 512 + d];
          Cf[(long)grow * 512 + d] = val;
        }
      }
    }
  } else {
#pragma unroll
    for (int mi = 0; mi < 4; mi++) {
#pragma unroll
      for (int ni = 0; ni < 4; ni++) {
        int gcol = colBase + wcol + ni * 16 + l15;
        float bcol = (BIAS == 1) ? bias[gcol] : 0.0f;
#pragma unroll
        for (int r = 0; r < 4; r++) {
          int grow = rowBase + wrow + mi * 16 + quad * 4 + r;
          float val = acc[mi][ni][r] * scale + bcol + ((BIAS == 2) ? bias[grow] : 0.0f);
          long off = zC + (long)grow * ldc + gcol;
          if (WBF16) Cb[off] = f2bf(val);
          else       Cf[off] = val;
        }
      }
    }
  }
}

// ---------------- LN1 (reads pre-residual glu+x), writes fp32 + bf16 ----------------
__global__ __launch_bounds__(128)
void k_ln(const float* __restrict__ src, const float* __restrict__ w, const float* __restrict__ b,
          float* __restrict__ outf, ushortT* __restrict__ outb)
{
  __shared__ float s1[2], s2[2];
  long r = blockIdx.x;
  int tid = threadIdx.x;
  floatx4 v = *(const floatx4*)&src[r * 512 + tid * 4];
  float sum = v[0] + v[1] + v[2] + v[3];
  float ssq = v[0]*v[0] + v[1]*v[1] + v[2]*v[2] + v[3]*v[3];
#pragma unroll
  for (int off = 32; off; off >>= 1) { sum += __shfl_xor(sum, off); ssq += __shfl_xor(ssq, off); }
  if ((tid & 63) == 0) { s1[tid >> 6] = sum; s2[tid >> 6] = ssq; }
  __syncthreads();
  sum = s1[0] + s1[1]; ssq = s2[0] + s2[1];
  float mu = sum * (1.0f / 512.0f);
  float var = ssq * (1.0f / 512.0f) - mu * mu;
  float rstd = rsqrtf(var + 1e-5f);
  floatx4 wv = *(const floatx4*)&w[tid * 4];
  floatx4 bv = *(const floatx4*)&b[tid * 4];
  floatx4 o; ushort4v ob;
#pragma unroll
  for (int j = 0; j < 4; j++) { o[j] = (v[j] - mu) * rstd * wv[j] + bv[j]; ob[j] = f2bf(o[j]); }
  *(floatx4*)&outf[r * 512 + tid * 4] = o;
  *(ushort4v*)&outb[r * 512 + tid * 4] = ob;
}

// ---------------- residual + LN2 ----------------
__global__ __launch_bounds__(128)
void k_add_ln(const float* __restrict__ h, const float* __restrict__ c,
              const float* __restrict__ w, const float* __restrict__ b,
              float* __restrict__ out)
{
  __shared__ float s1[2], s2[2];
  long r = blockIdx.x;
  int tid = threadIdx.x;
  floatx4 v = *(const floatx4*)&h[r * 512 + tid * 4];
  floatx4 cv = *(const floatx4*)&c[r * 512 + tid * 4];
#pragma unroll
  for (int j = 0; j < 4; j++) v[j] += cv[j];
  float sum = v[0] + v[1] + v[2] + v[3];
  float ssq = v[0]*v[0] + v[1]*v[1] + v[2]*v[2] + v[3]*v[3];
#pragma unroll
  for (int off = 32; off; off >>= 1) { sum += __shfl_xor(sum, off); ssq += __shfl_xor(ssq, off); }
  if ((tid & 63) == 0) { s1[tid >> 6] = sum; s2[tid >> 6] = ssq; }
  __syncthreads();
  sum = s1[0] + s1[1]; ssq = s2[0] + s2[1];
  float mu = sum * (1.0f / 512.0f);
  float var = ssq * (1.0f / 512.0f) - mu * mu;
  float rstd = rsqrtf(var + 1e-5f);
  floatx4 wv = *(const floatx4*)&w[tid * 4];
  floatx4 bv = *(const floatx4*)&b[tid * 4];
  floatx4 o;
#pragma unroll
  for (int j = 0; j < 4; j++) o[j] = (v[j] - mu) * rstd * wv[j] + bv[j];
  *(floatx4*)&out[r * 512 + tid * 4] = o;
}

// ---------------- softmax over S=2048, in place + bf16 copy ----------------
__global__ __launch_bounds__(256)
void k_softmax(float* __restrict__ attn, ushortT* __restrict__ attnbf)
{
  __shared__ float sred[4];
  long r = blockIdx.x;
  float* row = attn + r * 2048;
  ushortT* brow = attnbf + r * 2048;
  int tid = threadIdx.x;
  floatx4 v0 = *(const floatx4*)&row[tid * 4];
  floatx4 v1 = *(const floatx4*)&row[1024 + tid * 4];
  float mx = fmaxf(fmaxf(fmaxf(v0[0], v0[1]), fmaxf(v0[2], v0[3])),
                   fmaxf(fmaxf(v1[0], v1[1]), fmaxf(v1[2], v1[3])));
#pragma unroll
  for (int off = 32; off; off >>= 1) mx = fmaxf(mx, __shfl_xor(mx, off));
  if ((tid & 63) == 0) sred[tid >> 6] = mx;
  __syncthreads();
  mx = fmaxf(fmaxf(sred[0], sred[1]), fmaxf(sred[2], sred[3]));
  __syncthreads();
  float sum = 0.f;
#pragma unroll
  for (int j = 0; j < 4; j++) { v0[j] = __expf(v0[j] - mx); sum += v0[j]; }
#pragma unroll
  for (int j = 0; j < 4; j++) { v1[j] = __expf(v1[j] - mx); sum += v1[j]; }
#pragma unroll
  for (int off = 32; off; off >>= 1) sum += __shfl_xor(sum, off);
  if ((tid & 63) == 0) sred[tid >> 6] = sum;
  __syncthreads();
  sum = sred[0] + sred[1] + sred[2] + sred[3];
  float inv = 1.0f / sum;
  ushort4v b0, b1;
#pragma unroll
  for (int j = 0; j < 4; j++) { v0[j] *= inv; v1[j] *= inv; b0[j] = f2bf(v0[j]); b1[j] = f2bf(v1[j]); }
  *(floatx4*)&row[tid * 4] = v0;
  *(floatx4*)&row[1024 + tid * 4] = v1;
  *(ushort4v*)&brow[tid * 4] = b0;
  *(ushort4v*)&brow[1024 + tid * 4] = b1;
}

extern "C" void kernel_launch(void* const* d_in, const int* in_sizes, int n_in,
                              void* d_out, int out_size, void* d_ws, size_t ws_size,
                              hipStream_t stream)
{
  const float* x      = (const float*)d_in[0];
  const float* enc    = (const float*)d_in[1];
  const float* conv_w = (const float*)d_in[2];
  const float* conv_b = (const float*)d_in[3];
  const float* ln1_w  = (const float*)d_in[4];
  const float* ln1_b  = (const float*)d_in[5];
  const float* Wq     = (const float*)d_in[6];
  const float* bq     = (const float*)d_in[7];
  const float* Wk     = (const float*)d_in[8];
  const float* bk     = (const float*)d_in[9];
  const float* Wv     = (const float*)d_in[10];
  const float* bv     = (const float*)d_in[11];
  const float* Wo     = (const float*)d_in[12];
  const float* bo     = (const float*)d_in[13];
  const float* ln2_w  = (const float*)d_in[14];
  const float* ln2_b  = (const float*)d_in[15];

  const long BT = 16384, Dd = 512, S = 2048, TT = 2048;
  float* out  = (float*)d_out;
  float* attn = out + BT * Dd;

  char* p = (char*)d_ws;
  auto alloc = [&](size_t bytes) { char* r = p; p += (bytes + 255) & ~255UL; return r; };
  float*   hglu  = (float*)alloc(BT * Dd * 4);      // reused as ctxo after k_ln consumes it
  float*   h_f   = (float*)alloc(BT * Dd * 4);
  ushortT* xpad  = (ushortT*)alloc(8L * 2050 * 512 * 2);
  ushortT* encbf = (ushortT*)alloc(BT * Dd * 2);
  ushortT* hbf   = (ushortT*)alloc(BT * Dd * 2);
  ushortT* qbf   = (ushortT*)alloc(BT * Dd * 2);
  ushortT* kbf   = (ushortT*)alloc(BT * Dd * 2);
  ushortT* vT    = (ushortT*)alloc(Dd * BT * 2);    // [512][16384], col = b*2048+t
  ushortT* ctxbf = (ushortT*)alloc(BT * Dd * 2);
  ushortT* attnbf= (ushortT*)alloc(BT * S * 2);
  ushortT* Wcbf  = (ushortT*)alloc(1024L * 1536 * 2);
  ushortT* Wqbf  = (ushortT*)alloc(Dd * Dd * 2);
  ushortT* Wkbf  = (ushortT*)alloc(Dd * Dd * 2);
  ushortT* Wvbf  = (ushortT*)alloc(Dd * Dd * 2);
  ushortT* Wobf  = (ushortT*)alloc(Dd * Dd * 2);

  // conversions
  k_xpad<<<8 * 2050, 128, 0, stream>>>(x, xpad);
  k_f32_to_bf16v<<<(BT * Dd / 4 + 255) / 256, 256, 0, stream>>>(enc, encbf, BT * Dd / 4);
  k_convw<<<(1024 * 1536 + 255) / 256, 256, 0, stream>>>(conv_w, Wcbf);
  k_f32_to_bf16v<<<(Dd * Dd / 4 + 255) / 256, 256, 0, stream>>>(Wq, Wqbf, Dd * Dd / 4);
  k_f32_to_bf16v<<<(Dd * Dd / 4 + 255) / 256, 256, 0, stream>>>(Wk, Wkbf, Dd * Dd / 4);
  k_f32_to_bf16v<<<(Dd * Dd / 4 + 255) / 256, 256, 0, stream>>>(Wv, Wvbf, Dd * Dd / 4);
  k_f32_to_bf16v<<<(Dd * Dd / 4 + 255) / 256, 256, 0, stream>>>(Wo, Wobf, Dd * Dd / 4);

  // conv GEMM + fused GLU + residual -> hglu fp32 [16384,512]
  k_gemm<1, 1, 1, 0><<<dim3(128, 8), 256, 0, stream>>>(
      xpad, 0, 0, Wcbf, 0, 1536, conv_b, x, hglu, nullptr, 0, 512, 1536, 1.0f);
  // LN1 -> h_f fp32 + hbf bf16
  k_ln<<<16384, 128, 0, stream>>>(hglu, ln1_w, ln1_b, h_f, hbf);

  // q = h @ Wq^T + bq (bf16)
  k_gemm<0, 1, 0, 1><<<dim3(128, 4), 256, 0, stream>>>(
      hbf, 0, 512, Wqbf, 0, 512, bq, nullptr, nullptr, qbf, 0, 512, 512, 1.0f);
  // k = enc @ Wk^T + bk (bf16)
  k_gemm<0, 1, 0, 1><<<dim3(128, 4), 256, 0, stream>>>(
      encbf, 0, 512, Wkbf, 0, 512, bk, nullptr, nullptr, kbf, 0, 512, 512, 1.0f);
  // vT = Wv @ enc^T + bv (row bias) -> [512][16384] bf16
  k_gemm<0, 2, 0, 1><<<dim3(4, 128), 256, 0, stream>>>(
      Wvbf, 0, 512, encbf, 0, 512, bv, nullptr, nullptr, vT, 0, 16384, 512, 1.0f);

  // scores = q @ k^T / sqrt(512) -> attn fp32 (d_out)
  k_gemm<0, 0, 0, 0><<<dim3(16, 16, 8), 256, 0, stream>>>(
      qbf, TT * Dd, 512, kbf, S * Dd, 512, nullptr, nullptr,
      attn, nullptr, TT * S, 2048, 512, 0.04419417382415922f);
  // softmax in place + bf16 copy
  k_softmax<<<16384, 256, 0, stream>>>(attn, attnbf);

  // ctx = attn @ v : A = attnbf [T,S], B^T = vT [512][16384] (bBatch = col offset 2048)
  k_gemm<0, 0, 0, 1><<<dim3(16, 4, 8), 256, 0, stream>>>(
      attnbf, TT * S, 2048, vT, TT, 16384, nullptr, nullptr,
      nullptr, ctxbf, TT * Dd, 512, 2048, 1.0f);

  // out-proj: ctx @ Wo^T + bo -> ctxo fp32 (reuse hglu)
  float* ctxo = hglu;
  k_gemm<0, 1, 0, 0><<<dim3(128, 4), 256, 0, stream>>>(
      ctxbf, 0, 512, Wobf, 0, 512, bo, nullptr, ctxo, nullptr, 0, 512, 512, 1.0f);
  // LN2 -> out
  k_add_ln<<<16384, 128, 0, stream>>>(h_f, ctxo, ln2_w, ln2_b, out);
}

// Round 3
// 587.931 us; speedup vs baseline: 1.2895x; 1.0363x over previous
//
#include <hip/hip_runtime.h>
#include <hip/hip_bf16.h>
#include <stdint.h>

// ConvDecoderLayer: B=8, T=S=2048, D=512, K=3
// out = (LN2(h + (attn@v)@Wo^T + bo), attn), h = LN1(GLU(causal_conv(x)) + x)

typedef unsigned short ushortT;
typedef __bf16 bf16x8 __attribute__((ext_vector_type(8)));
typedef float floatx4 __attribute__((ext_vector_type(4)));
typedef unsigned short ushort4v __attribute__((ext_vector_type(4)));
typedef unsigned short ushort8 __attribute__((ext_vector_type(8)));

__device__ __forceinline__ ushortT f2bf(float f) {
  unsigned u = __builtin_bit_cast(unsigned, f);
  u += 0x7FFFu + ((u >> 16) & 1u);   // RNE
  return (ushortT)(u >> 16);
}
__device__ __forceinline__ float bf2f(ushortT u) {
  return __builtin_bit_cast(float, (unsigned)u << 16);
}

__device__ __forceinline__ void gload_lds16(const void* g, void* l) {
  __builtin_amdgcn_global_load_lds(
      (const __attribute__((address_space(1))) void*)g,
      (__attribute__((address_space(3))) void*)l, 16, 0, 0);
}

// ---------------- conversion kernels ----------------
__global__ __launch_bounds__(256)
void k_f32_to_bf16v(const float* __restrict__ src, ushortT* __restrict__ dst, long n4) {
  long i = (long)blockIdx.x * 256 + threadIdx.x;
  if (i >= n4) return;
  floatx4 v = *(const floatx4*)&src[i * 4];
  ushort4v o;
#pragma unroll
  for (int j = 0; j < 4; j++) o[j] = f2bf(v[j]);
  *(ushort4v*)&dst[i * 4] = o;
}

// four 512x512 weights -> bf16, one launch
__global__ __launch_bounds__(256)
void k_w4(const float* __restrict__ w0, const float* __restrict__ w1,
          const float* __restrict__ w2, const float* __restrict__ w3,
          ushortT* __restrict__ dst) {
  long i = (long)blockIdx.x * 256 + threadIdx.x;   // float4 groups, 4*65536 total
  int m = (int)(i >> 16);
  long within = (i & 65535) * 4;
  const float* s = (m == 0) ? w0 : (m == 1) ? w1 : (m == 2) ? w2 : w3;
  floatx4 v = *(const floatx4*)&s[within];
  ushort4v o;
#pragma unroll
  for (int j = 0; j < 4; j++) o[j] = f2bf(v[j]);
  *(ushort4v*)&dst[(long)m * 262144 + within] = o;
}

// x [8,2048,512] f32 -> xpad [8,2050,512] bf16 with 2 leading zero rows per batch
__global__ __launch_bounds__(128)
void k_xpad(const float* __restrict__ x, ushortT* __restrict__ xp) {
  int row = blockIdx.x;                 // 8*2050
  int b = row / 2050, tp = row % 2050;
  int c = threadIdx.x * 4;
  ushort4v o = {0, 0, 0, 0};
  if (tp >= 2) {
    floatx4 v = *(const floatx4*)&x[((long)(b * 2048 + tp - 2)) * 512 + c];
#pragma unroll
    for (int j = 0; j < 4; j++) o[j] = f2bf(v[j]);
  }
  *(ushort4v*)&xp[(long)row * 512 + c] = o;
}

// conv_w [1024][512][3] -> interleaved B^T form Wc'[n][kk], kk = tap*512+i
__global__ __launch_bounds__(256)
void k_convw(const float* __restrict__ w, ushortT* __restrict__ dst) {
  long idx = (long)blockIdx.x * 256 + threadIdx.x;
  if (idx >= 1024L * 1536) return;
  int n = (int)(idx / 1536), kk = (int)(idx % 1536);
  int tap = kk >> 9, i = kk & 511;
  int o = ((n >> 4) & 1) * 512 + (n >> 5) * 16 + (n & 15);
  dst[idx] = f2bf(w[(o * 512 + i) * 3 + tap]);
}

// ---------------- GEMM ----------------
template<int CONV_A, int BIAS, int GLU, int WBF16, int SWAP = 0>
__global__ __launch_bounds__(256)
void k_gemm(const ushortT* __restrict__ A, long aBatch, int lda,
            const ushortT* __restrict__ Bm, long bBatch, int ldb,
            const float* __restrict__ bias, const float* __restrict__ xres,
            float* __restrict__ Cf, ushortT* __restrict__ Cb, long cBatch, int ldc,
            int Kdim, float scale)
{
  __shared__ ushortT As[128 * 32];
  __shared__ ushortT Bs[128 * 32];
  const int tid  = threadIdx.x;
  const int lane = tid & 63;
  const int wave = tid >> 6;
  const int wrow = (wave >> 1) * 64;
  const int wcol = (wave & 1) * 64;
  const int l15  = lane & 15;
  const int quad = lane >> 4;
  const long zA = (long)blockIdx.z * aBatch;
  const long zB = (long)blockIdx.z * bBatch;
  const long zC = (long)blockIdx.z * cBatch;
  const int rowBase = (SWAP ? blockIdx.y : blockIdx.x) * 128;
  const int colBase = (SWAP ? blockIdx.x : blockIdx.y) * 128;

  floatx4 zero = {0.f, 0.f, 0.f, 0.f};
  floatx4 acc[4][4];
#pragma unroll
  for (int mi = 0; mi < 4; mi++)
#pragma unroll
    for (int ni = 0; ni < 4; ni++) acc[mi][ni] = zero;

  for (int k0 = 0; k0 < Kdim; k0 += 32) {
    __syncthreads();
    {
      int ch = tid;
#pragma unroll
      for (int it = 0; it < 2; it++, ch += 256) {
        int row = ch >> 2, c8 = (ch & 3) << 3;
        if (CONV_A) {
          int gr = rowBase + row, gc = k0 + c8;
          int tap = gc >> 9, ii = gc & 511;
          int b = gr >> 11, t = gr & 2047;
          long gofs = ((long)(b * 2050 + t + tap) << 9) + ii;
          gload_lds16(A + gofs, &As[ch * 8]);
        } else {
          long gofs = zA + (long)(rowBase + row) * lda + (k0 + c8);
          gload_lds16(A + gofs, &As[ch * 8]);
        }
      }
      ch = tid;
#pragma unroll
      for (int it = 0; it < 2; it++, ch += 256) {
        int row = ch >> 2, c8 = (ch & 3) << 3;
        long gofs = zB + (long)(colBase + row) * ldb + (k0 + c8);
        gload_lds16(Bm + gofs, &Bs[ch * 8]);
      }
    }
    __syncthreads();
    bf16x8 av[4], bv[4];
#pragma unroll
    for (int mi = 0; mi < 4; mi++)
      av[mi] = *(const bf16x8*)&As[(wrow + mi * 16 + l15) * 32 + quad * 8];
#pragma unroll
    for (int ni = 0; ni < 4; ni++)
      bv[ni] = *(const bf16x8*)&Bs[(wcol + ni * 16 + l15) * 32 + quad * 8];
#pragma unroll
    for (int mi = 0; mi < 4; mi++)
#pragma unroll
      for (int ni = 0; ni < 4; ni++)
        acc[mi][ni] = __builtin_amdgcn_mfma_f32_16x16x32_bf16(av[mi], bv[ni], acc[mi][ni], 0, 0, 0);
  }

  if (GLU) {
#pragma unroll
    for (int mi = 0; mi < 4; mi++) {
#pragma unroll
      for (int ni = 0; ni < 4; ni += 2) {
        int colA = colBase + wcol + ni * 16;
        int d = (colA >> 5) * 16 + l15;
        float ba = bias[d], bg = bias[512 + d];
#pragma unroll
        for (int r = 0; r < 4; r++) {
          int grow = rowBase + wrow + mi * 16 + quad * 4 + r;
          float a = acc[mi][ni][r] + ba;
          float g = acc[mi][ni + 1][r] + bg;
          float val = a / (1.0f + __expf(-g)) + xres[(long)grow * 512 + d];
          Cf[(long)grow * 512 + d] = val;
        }
      }
    }
  } else {
#pragma unroll
    for (int mi = 0; mi < 4; mi++) {
#pragma unroll
      for (int ni = 0; ni < 4; ni++) {
        int gcol = colBase + wcol + ni * 16 + l15;
        float bcol = (BIAS == 1) ? bias[gcol] : 0.0f;
#pragma unroll
        for (int r = 0; r < 4; r++) {
          int grow = rowBase + wrow + mi * 16 + quad * 4 + r;
          float val = acc[mi][ni][r] * scale + bcol + ((BIAS == 2) ? bias[grow] : 0.0f);
          long off = zC + (long)grow * ldc + gcol;
          if (WBF16) Cb[off] = f2bf(val);
          else       Cf[off] = val;
        }
      }
    }
  }
}

// ---------------- LN1 -> bf16 only ----------------
__global__ __launch_bounds__(128)
void k_ln(const float* __restrict__ src, const float* __restrict__ w, const float* __restrict__ b,
          ushortT* __restrict__ outb)
{
  __shared__ float s1[2], s2[2];
  long r = blockIdx.x;
  int tid = threadIdx.x;
  floatx4 v = *(const floatx4*)&src[r * 512 + tid * 4];
  float sum = v[0] + v[1] + v[2] + v[3];
  float ssq = v[0]*v[0] + v[1]*v[1] + v[2]*v[2] + v[3]*v[3];
#pragma unroll
  for (int off = 32; off; off >>= 1) { sum += __shfl_xor(sum, off); ssq += __shfl_xor(ssq, off); }
  if ((tid & 63) == 0) { s1[tid >> 6] = sum; s2[tid >> 6] = ssq; }
  __syncthreads();
  sum = s1[0] + s1[1]; ssq = s2[0] + s2[1];
  float mu = sum * (1.0f / 512.0f);
  float var = ssq * (1.0f / 512.0f) - mu * mu;
  float rstd = rsqrtf(var + 1e-5f);
  floatx4 wv = *(const floatx4*)&w[tid * 4];
  floatx4 bv = *(const floatx4*)&b[tid * 4];
  ushort4v ob;
#pragma unroll
  for (int j = 0; j < 4; j++) ob[j] = f2bf((v[j] - mu) * rstd * wv[j] + bv[j]);
  *(ushort4v*)&outb[r * 512 + tid * 4] = ob;
}

// ---------------- softmax: bf16 logits -> fp32 attn (d_out) + bf16 P in place ----------------
__global__ __launch_bounds__(256)
void k_softmax(ushortT* __restrict__ logits, float* __restrict__ attn)
{
  __shared__ float sred[4];
  long r = blockIdx.x;
  ushortT* lrow = logits + r * 2048;
  float* arow = attn + r * 2048;
  int tid = threadIdx.x;
  ushort8 uv = *(const ushort8*)&lrow[tid * 8];
  float v[8];
#pragma unroll
  for (int j = 0; j < 8; j++) v[j] = bf2f(uv[j]);
  float mx = v[0];
#pragma unroll
  for (int j = 1; j < 8; j++) mx = fmaxf(mx, v[j]);
#pragma unroll
  for (int off = 32; off; off >>= 1) mx = fmaxf(mx, __shfl_xor(mx, off));
  if ((tid & 63) == 0) sred[tid >> 6] = mx;
  __syncthreads();
  mx = fmaxf(fmaxf(sred[0], sred[1]), fmaxf(sred[2], sred[3]));
  __syncthreads();
  float sum = 0.f;
#pragma unroll
  for (int j = 0; j < 8; j++) { v[j] = __expf(v[j] - mx); sum += v[j]; }
#pragma unroll
  for (int off = 32; off; off >>= 1) sum += __shfl_xor(sum, off);
  if ((tid & 63) == 0) sred[tid >> 6] = sum;
  __syncthreads();
  sum = sred[0] + sred[1] + sred[2] + sred[3];
  float inv = 1.0f / sum;
  floatx4 o0, o1;
  ushort8 ob;
#pragma unroll
  for (int j = 0; j < 8; j++) {
    float p = v[j] * inv;
    if (j < 4) o0[j] = p; else o1[j - 4] = p;
    ob[j] = f2bf(p);
  }
  *(floatx4*)&arow[tid * 8] = o0;
  *(floatx4*)&arow[tid * 8 + 4] = o1;
  *(ushort8*)&lrow[tid * 8] = ob;
}

// ---------------- fused out-proj + residual + LN2 ----------------
// 32 rows x 512 cols per block; wave w owns cols [128w, 128w+128)
__global__ __launch_bounds__(256)
void k_oproj_ln(const ushortT* __restrict__ ctx, const ushortT* __restrict__ Wo,
                const float* __restrict__ bo, const ushortT* __restrict__ h,
                const float* __restrict__ w, const float* __restrict__ b,
                float* __restrict__ out)
{
  __shared__ ushortT As[32 * 32];
  __shared__ ushortT Bs[512 * 32];
  __shared__ float psum[4][32], pssq[4][32];
  const int tid = threadIdx.x, lane = tid & 63, wave = tid >> 6;
  const int l15 = lane & 15, quad = lane >> 4;
  const int rowBase = blockIdx.x * 32;

  floatx4 zero = {0.f, 0.f, 0.f, 0.f};
  floatx4 acc[2][8];
#pragma unroll
  for (int mi = 0; mi < 2; mi++)
#pragma unroll
    for (int ni = 0; ni < 8; ni++) acc[mi][ni] = zero;

  for (int k0 = 0; k0 < 512; k0 += 32) {
    __syncthreads();
    if (tid < 128)
      gload_lds16(ctx + (long)(rowBase + (tid >> 2)) * 512 + k0 + ((tid & 3) << 3), &As[tid * 8]);
#pragma unroll
    for (int it = 0; it < 8; it++) {
      int ch = tid + it * 256;
      gload_lds16(Wo + (long)(ch >> 2) * 512 + k0 + ((ch & 3) << 3), &Bs[ch * 8]);
    }
    __syncthreads();
    bf16x8 av[2], bv[8];
#pragma unroll
    for (int mi = 0; mi < 2; mi++)
      av[mi] = *(const bf16x8*)&As[(mi * 16 + l15) * 32 + quad * 8];
#pragma unroll
    for (int ni = 0; ni < 8; ni++)
      bv[ni] = *(const bf16x8*)&Bs[(wave * 128 + ni * 16 + l15) * 32 + quad * 8];
#pragma unroll
    for (int mi = 0; mi < 2; mi++)
#pragma unroll
      for (int ni = 0; ni < 8; ni++)
        acc[mi][ni] = __builtin_amdgcn_mfma_f32_16x16x32_bf16(av[mi], bv[ni], acc[mi][ni], 0, 0, 0);
  }

  float lnw[8], lnb[8], bov[8];
#pragma unroll
  for (int ni = 0; ni < 8; ni++) {
    int col = wave * 128 + ni * 16 + l15;
    bov[ni] = bo[col]; lnw[ni] = w[col]; lnb[ni] = b[col];
  }
#pragma unroll
  for (int mi = 0; mi < 2; mi++) {
#pragma unroll
    for (int r = 0; r < 4; r++) {
      long grow = rowBase + mi * 16 + quad * 4 + r;
      float ps = 0.f, pq = 0.f;
#pragma unroll
      for (int ni = 0; ni < 8; ni++) {
        int col = wave * 128 + ni * 16 + l15;
        float val = acc[mi][ni][r] + bov[ni] + bf2f(h[grow * 512 + col]);
        acc[mi][ni][r] = val;
        ps += val; pq += val * val;
      }
#pragma unroll
      for (int off = 1; off < 16; off <<= 1) { ps += __shfl_xor(ps, off); pq += __shfl_xor(pq, off); }
      if (l15 == 0) { int rl = mi * 16 + quad * 4 + r; psum[wave][rl] = ps; pssq[wave][rl] = pq; }
    }
  }
  __syncthreads();
#pragma unroll
  for (int mi = 0; mi < 2; mi++) {
#pragma unroll
    for (int r = 0; r < 4; r++) {
      int rl = mi * 16 + quad * 4 + r;
      float S = psum[0][rl] + psum[1][rl] + psum[2][rl] + psum[3][rl];
      float Q = pssq[0][rl] + pssq[1][rl] + pssq[2][rl] + pssq[3][rl];
      float mu = S * (1.0f / 512.0f);
      float rstd = rsqrtf(Q * (1.0f / 512.0f) - mu * mu + 1e-5f);
      long grow = rowBase + rl;
#pragma unroll
      for (int ni = 0; ni < 8; ni++) {
        int col = wave * 128 + ni * 16 + l15;
        out[grow * 512 + col] = (acc[mi][ni][r] - mu) * rstd * lnw[ni] + lnb[ni];
      }
    }
  }
}

extern "C" void kernel_launch(void* const* d_in, const int* in_sizes, int n_in,
                              void* d_out, int out_size, void* d_ws, size_t ws_size,
                              hipStream_t stream)
{
  const float* x      = (const float*)d_in[0];
  const float* enc    = (const float*)d_in[1];
  const float* conv_w = (const float*)d_in[2];
  const float* conv_b = (const float*)d_in[3];
  const float* ln1_w  = (const float*)d_in[4];
  const float* ln1_b  = (const float*)d_in[5];
  const float* Wq     = (const float*)d_in[6];
  const float* bq     = (const float*)d_in[7];
  const float* Wk     = (const float*)d_in[8];
  const float* bk     = (const float*)d_in[9];
  const float* Wv     = (const float*)d_in[10];
  const float* bv     = (const float*)d_in[11];
  const float* Wo     = (const float*)d_in[12];
  const float* bo     = (const float*)d_in[13];
  const float* ln2_w  = (const float*)d_in[14];
  const float* ln2_b  = (const float*)d_in[15];

  const long BT = 16384, Dd = 512, S = 2048, TT = 2048;
  float* out  = (float*)d_out;
  float* attn = out + BT * Dd;

  char* p = (char*)d_ws;
  auto alloc = [&](size_t bytes) { char* r = p; p += (bytes + 255) & ~255UL; return r; };
  float*   hglu  = (float*)alloc(BT * Dd * 4);
  ushortT* xpad  = (ushortT*)alloc(8L * 2050 * 512 * 2);
  ushortT* encbf = (ushortT*)alloc(BT * Dd * 2);
  ushortT* hbf   = (ushortT*)alloc(BT * Dd * 2);
  ushortT* qbf   = (ushortT*)alloc(BT * Dd * 2);
  ushortT* kbf   = (ushortT*)alloc(BT * Dd * 2);
  ushortT* vT    = (ushortT*)alloc(Dd * BT * 2);    // [512][16384]
  ushortT* ctxbf = (ushortT*)alloc(BT * Dd * 2);
  ushortT* sl    = (ushortT*)alloc(BT * S * 2);     // logits, then P (bf16)
  ushortT* Wcbf  = (ushortT*)alloc(1024L * 1536 * 2);
  ushortT* wall  = (ushortT*)alloc(4L * 262144 * 2);
  ushortT* Wqbf = wall, *Wkbf = wall + 262144, *Wvbf = wall + 2 * 262144, *Wobf = wall + 3 * 262144;

  // conversions
  k_xpad<<<8 * 2050, 128, 0, stream>>>(x, xpad);
  k_f32_to_bf16v<<<(BT * Dd / 4 + 255) / 256, 256, 0, stream>>>(enc, encbf, BT * Dd / 4);
  k_convw<<<(1024 * 1536 + 255) / 256, 256, 0, stream>>>(conv_w, Wcbf);
  k_w4<<<1024, 256, 0, stream>>>(Wq, Wk, Wv, Wo, wall);

  // conv GEMM + fused GLU + residual -> hglu fp32
  k_gemm<1, 1, 1, 0><<<dim3(128, 8), 256, 0, stream>>>(
      xpad, 0, 0, Wcbf, 0, 1536, conv_b, x, hglu, nullptr, 0, 512, 1536, 1.0f);
  // LN1 -> hbf bf16
  k_ln<<<16384, 128, 0, stream>>>(hglu, ln1_w, ln1_b, hbf);

  // q = h @ Wq^T + bq
  k_gemm<0, 1, 0, 1><<<dim3(128, 4), 256, 0, stream>>>(
      hbf, 0, 512, Wqbf, 0, 512, bq, nullptr, nullptr, qbf, 0, 512, 512, 1.0f);
  // k = enc @ Wk^T + bk
  k_gemm<0, 1, 0, 1><<<dim3(128, 4), 256, 0, stream>>>(
      encbf, 0, 512, Wkbf, 0, 512, bk, nullptr, nullptr, kbf, 0, 512, 512, 1.0f);
  // vT = Wv @ enc^T + bv (row bias) -> [512][16384]
  k_gemm<0, 2, 0, 1><<<dim3(4, 128), 256, 0, stream>>>(
      Wvbf, 0, 512, encbf, 0, 512, bv, nullptr, nullptr, vT, 0, 16384, 512, 1.0f);

  // scores -> bf16 logits in sl
  k_gemm<0, 0, 0, 1><<<dim3(16, 16, 8), 256, 0, stream>>>(
      qbf, TT * Dd, 512, kbf, S * Dd, 512, nullptr, nullptr,
      nullptr, sl, TT * S, 2048, 512, 0.04419417382415922f);
  // softmax: sl -> attn fp32 (d_out) + P bf16 in place
  k_softmax<<<16384, 256, 0, stream>>>(sl, attn);

  // ctx = P @ v : A = sl [T,S], B^T = vT; SWAP grid so consecutive blocks share A-tile
  k_gemm<0, 0, 0, 1, 1><<<dim3(4, 16, 8), 256, 0, stream>>>(
      sl, TT * S, 2048, vT, TT, 16384, nullptr, nullptr,
      nullptr, ctxbf, TT * Dd, 512, 2048, 1.0f);

  // fused out-proj + residual + LN2 -> out
  k_oproj_ln<<<512, 256, 0, stream>>>(ctxbf, Wobf, bo, hbf, ln2_w, ln2_b, out);
}